// Round 6
// baseline (21338.715 us; speedup 1.0000x reference)
//
#include <hip/hip_runtime.h>
#include <hip/hip_bf16.h>
#include <cstdint>
#include <cstddef>

// SimpleXLSTM persistent-kernel round 6.
// vs round 5: (1) __launch_bounds__(1024,4) -> 128-VGPR budget so the 4-deep
// prefetch ring actually lives in registers (round 5 was silently squeezed to
// 64 VGPRs -> pipeline collapsed, latency-bound). (2) fused tri-section
// K-loop (x | h0prev | h1prev): layer0+layer1 share one pass over h0prev
// (4 MFMA per A-load there), cutting per-block h traffic 768->512 KB/phase.
// Ring buffers / periodic fence / hierarchical barrier identical to round 5.

#define BATCH 128
#define SEQ   512
#define INP   512
#define HID   1024
#define NCOL  4096
#define NB    256
#define KS0   48
#define KS1   64

typedef __bf16 bf16x8 __attribute__((ext_vector_type(8)));
typedef float  f32x4  __attribute__((ext_vector_type(4)));
typedef unsigned int u32x4 __attribute__((ext_vector_type(4)));
typedef unsigned long long u64;
typedef u64 u64x2 __attribute__((ext_vector_type(2)));

#define OFF_W0   0        // 49152
#define OFF_W1   49152    // 65536
#define LDS_DYN  114688

__device__ __forceinline__ bf16x8 load_bf16x8(const __hip_bfloat16* p) {
    u32x4 u = *reinterpret_cast<const u32x4*>(p);
    return __builtin_bit_cast(bf16x8, u);
}
__device__ __forceinline__ bf16x8 aload_bf16x8(const __hip_bfloat16* p) {
    u64x2 q;
    q[0] = __hip_atomic_load((const u64*)p,       __ATOMIC_RELAXED, __HIP_MEMORY_SCOPE_AGENT);
    q[1] = __hip_atomic_load((const u64*)(p + 4), __ATOMIC_RELAXED, __HIP_MEMORY_SCOPE_AGENT);
    return __builtin_bit_cast(bf16x8, q);
}
__device__ __forceinline__ f32x4 mfma16(bf16x8 a, bf16x8 b, f32x4 c) {
    return __builtin_amdgcn_mfma_f32_16x16x32_bf16(a, b, c, 0, 0, 0);
}
__device__ __forceinline__ float sigmoidf_(float x) {
    return 1.0f / (1.0f + __expf(-x));
}
__device__ __forceinline__ float tanhf_(float x) {
    return 1.0f - 2.0f / (__expf(2.0f * x) + 1.0f);
}

// ---------------------------------------------------------------------------
// Prep kernels (verified rounds 2-5)
// ---------------------------------------------------------------------------
template<int Ks>
__global__ __launch_bounds__(1024)
void pack_frag_kernel(const float* __restrict__ W, __hip_bfloat16* __restrict__ F)
{
    __shared__ float tile[32][33];
    const int k0 = blockIdx.x * 32;
    const int c0 = blockIdx.y * 32;
    const int tx = threadIdx.x & 31, ty = threadIdx.x >> 5;
    tile[ty][tx] = W[(size_t)(k0 + ty) * NCOL + (c0 + tx)];
    __syncthreads();
    const int cL  = threadIdx.x >> 5;
    const int kgw = (threadIdx.x >> 3) & 3;
    const int j   = threadIdx.x & 7;
    const int c   = c0 + cL;
    const int r   = (c & 1023) * 4 + (c >> 10);
    const int nb2 = r >> 4, cl = r & 15;
    const int ks  = k0 >> 5;
    const size_t chunk = ((size_t)(nb2 * Ks + ks) * 4 + kgw) * 16 + cl;
    F[chunk * 8 + j] = __float2bfloat16(tile[kgw * 8 + j][cL]);
}

__global__ void bias_reorder_kernel(const float* __restrict__ b0,
                                    const float* __restrict__ b1,
                                    float* __restrict__ b0r,
                                    float* __restrict__ b1r)
{
    int i = blockIdx.x * blockDim.x + threadIdx.x;
    if (i >= 2 * NCOL) return;
    const float* src = (i < NCOL) ? b0 : b1;
    float*       dst = (i < NCOL) ? b0r : b1r;
    int c = i & (NCOL - 1);
    dst[(c & 1023) * 4 + (c >> 10)] = src[c];
}

__global__ __launch_bounds__(256)
void xconv_kernel(const float* __restrict__ x, __hip_bfloat16* __restrict__ xb)
{
    const size_t i = ((size_t)blockIdx.x * 256 + threadIdx.x) * 8;
    f32x4 a = *(const f32x4*)(x + i);
    f32x4 b = *(const f32x4*)(x + i + 4);
    bf16x8 v;
    #pragma unroll
    for (int e = 0; e < 4; ++e) { v[e] = (__bf16)a[e]; v[e + 4] = (__bf16)b[e]; }
    *reinterpret_cast<u32x4*>((__hip_bfloat16*)xb + i) = __builtin_bit_cast(u32x4, v);
}

// ---------------------------------------------------------------------------
// Persistent kernel.  FRESH: 64-slot rings + cached h loads + periodic fence.
// !FRESH fallback: 2-slot rings + bypass h loads.
// ---------------------------------------------------------------------------
template<bool XBF, bool FRESH>
__global__ __launch_bounds__(1024, 4)   // 4 waves/EU -> 128 VGPR budget
void lstm_persistent(const float* __restrict__ x,
                     const __hip_bfloat16* __restrict__ xb,
                     const __hip_bfloat16* __restrict__ F0,
                     const __hip_bfloat16* __restrict__ F1,
                     const float* __restrict__ b0r,
                     const float* __restrict__ b1r,
                     const float* __restrict__ Wout,
                     const float* __restrict__ bout,
                     __hip_bfloat16* __restrict__ h0r,
                     __hip_bfloat16* __restrict__ h1r,
                     float* __restrict__ out,
                     int* __restrict__ bar)
{
    constexpr int RMASK = FRESH ? 63 : 1;

    extern __shared__ char smem[];
    __hip_bfloat16* lW0 = (__hip_bfloat16*)(smem + OFF_W0);
    __hip_bfloat16* lW1 = (__hip_bfloat16*)(smem + OFF_W1);

    __shared__ float zacc[2][128][17];
    __shared__ float cS[2][512];
    __shared__ float biasS[2][16];
    __shared__ __hip_bfloat16 hstage[2][128][4];

    const int tid  = threadIdx.x;
    const int lane = tid & 63;
    const int wv   = tid >> 6;
    const int kq   = wv & 3;
    const int mq   = wv >> 2;
    const int lm   = lane & 15;
    const int kg   = lane >> 4;
    const int nb   = blockIdx.x;
    const int HS   = BATCH * HID;
    const int row0 = mq * 32 + lm;
    const int row1 = row0 + 16;

    // ---- one-time init ----
    {
        const u32x4* s0 = (const u32x4*)(F0 + (size_t)nb * (KS0 * 64 * 8));
        u32x4*       d0 = (u32x4*)lW0;
        for (int i = tid; i < KS0 * 64; i += 1024) d0[i] = s0[i];
        const u32x4* s1 = (const u32x4*)(F1 + (size_t)nb * (KS1 * 64 * 8));
        u32x4*       d1 = (u32x4*)lW1;
        for (int i = tid; i < KS1 * 64; i += 1024) d1[i] = s1[i];
        if (tid < 32) biasS[tid >> 4][tid & 15] =
            ((tid < 16) ? b0r : b1r)[nb * 16 + (tid & 15)];
        cS[tid >> 9][tid & 511] = 0.f;
        for (int i = tid; i < 2 * 128 * 17; i += 1024) ((float*)zacc)[i] = 0.f;
    }
    __syncthreads();

    for (int p = 0; p <= SEQ; ++p) {
        const __hip_bfloat16* h0prev = h0r + (size_t)((p + RMASK)     & RMASK) * HS; // h0(p-1)
        const __hip_bfloat16* h1prev = h1r + (size_t)((p + RMASK - 1) & RMASK) * HS; // h1(p-2)
        __hip_bfloat16*       h0w    = h0r + (size_t)( p              & RMASK) * HS; // h0(p)
        __hip_bfloat16*       h1w    = h1r + (size_t)((p + RMASK)     & RMASK) * HS; // h1(p-1)

        // ===== fused GEMM: layer0 (t=p) + layer1 (t=p-1), one pass =====
        // sections: u=0..3  : x(t)      -> accL0           (B0 frags ks 0..15)
        //           u=4..11 : h0prev    -> accL0 AND accL1 (B0 ks 16..47, B1 ks 0..31)
        //           u=12..19: h1prev    -> accL1           (B1 ks 32..63)
        {
            f32x4 aL0r0 = {0,0,0,0}, aL0r1 = {0,0,0,0};
            f32x4 aL1r0 = {0,0,0,0}, aL1r1 = {0,0,0,0};
            bf16x8 A0s[4], A1s[4], B0s[4], B1s[4];

            const size_t xoff = (size_t)(p < SEQ ? p : 0) * INP;   // clamp: p=SEQ discarded
            const __hip_bfloat16* hr0 = h0prev + (size_t)row0 * HID;
            const __hip_bfloat16* hr1 = h0prev + (size_t)row1 * HID;
            const __hip_bfloat16* qr0 = h1prev + (size_t)row0 * HID;
            const __hip_bfloat16* qr1 = h1prev + (size_t)row1 * HID;

            auto loadU = [&](int u, int s) {
                if (u < 4) {
                    const int ks = kq + 4 * u;
                    const int k  = ks * 32 + kg * 8;
                    B0s[s] = *(const bf16x8*)(lW0 + (size_t)(((ks * 4 + kg) * 16 + lm) * 8));
                    if constexpr (XBF) {
                        A0s[s] = load_bf16x8(xb + (size_t)row0 * (SEQ * INP) + xoff + k);
                        A1s[s] = load_bf16x8(xb + (size_t)row1 * (SEQ * INP) + xoff + k);
                    } else {
                        const float* p0 = x + (size_t)row0 * (SEQ * INP) + xoff + k;
                        const float* p1 = x + (size_t)row1 * (SEQ * INP) + xoff + k;
                        f32x4 a = *(const f32x4*)p0, b = *(const f32x4*)(p0 + 4);
                        f32x4 c = *(const f32x4*)p1, d = *(const f32x4*)(p1 + 4);
                        bf16x8 v0, v1;
                        #pragma unroll
                        for (int e = 0; e < 4; ++e) {
                            v0[e] = (__bf16)a[e]; v0[e + 4] = (__bf16)b[e];
                            v1[e] = (__bf16)c[e]; v1[e + 4] = (__bf16)d[e];
                        }
                        A0s[s] = v0; A1s[s] = v1;
                    }
                } else if (u < 12) {
                    const int ksh = kq + 4 * (u - 4);
                    const int k   = ksh * 32 + kg * 8;
                    B0s[s] = *(const bf16x8*)(lW0 + (size_t)((((16 + ksh) * 4 + kg) * 16 + lm) * 8));
                    B1s[s] = *(const bf16x8*)(lW1 + (size_t)(((ksh * 4 + kg) * 16 + lm) * 8));
                    if constexpr (FRESH) {
                        A0s[s] = load_bf16x8(hr0 + k);
                        A1s[s] = load_bf16x8(hr1 + k);
                    } else {
                        A0s[s] = aload_bf16x8(hr0 + k);
                        A1s[s] = aload_bf16x8(hr1 + k);
                    }
                } else {
                    const int ksq = kq + 4 * (u - 12);
                    const int k   = ksq * 32 + kg * 8;
                    B1s[s] = *(const bf16x8*)(lW1 + (size_t)((((32 + ksq) * 4 + kg) * 16 + lm) * 8));
                    if constexpr (FRESH) {
                        A0s[s] = load_bf16x8(qr0 + k);
                        A1s[s] = load_bf16x8(qr1 + k);
                    } else {
                        A0s[s] = aload_bf16x8(qr0 + k);
                        A1s[s] = aload_bf16x8(qr1 + k);
                    }
                }
            };

            #pragma unroll
            for (int u = 0; u < 4; ++u) loadU(u, u);
            #pragma unroll
            for (int u = 0; u < 20; ++u) {
                const int s = u & 3;
                if (u < 12) {
                    aL0r0 = mfma16(A0s[s], B0s[s], aL0r0);
                    aL0r1 = mfma16(A1s[s], B0s[s], aL0r1);
                }
                if (u >= 4) {
                    aL1r0 = mfma16(A0s[s], B1s[s], aL1r0);
                    aL1r1 = mfma16(A1s[s], B1s[s], aL1r1);
                }
                if (u < 16) loadU(u + 4, s);
            }

            if (p < SEQ) {
                #pragma unroll
                for (int r = 0; r < 4; ++r) {
                    atomicAdd(&zacc[0][mq * 32 + kg * 4 + r][lm],      aL0r0[r]);
                    atomicAdd(&zacc[0][mq * 32 + 16 + kg * 4 + r][lm], aL0r1[r]);
                }
            }
            if (p >= 1) {
                #pragma unroll
                for (int r = 0; r < 4; ++r) {
                    atomicAdd(&zacc[1][mq * 32 + kg * 4 + r][lm],      aL1r0[r]);
                    atomicAdd(&zacc[1][mq * 32 + 16 + kg * 4 + r][lm], aL1r1[r]);
                }
            }
        }
        __syncthreads();

        // ===== gates -> hstage (LDS) =====
        {
            const int L   = tid >> 9;
            const int idx = tid & 511;
            const int bl  = idx >> 2;
            const int u   = idx & 3;
            const bool act = L ? (p >= 1) : (p < SEQ);
            if (act) {
                float* zb = &zacc[L][bl][4 * u];
                const float zf = zb[0] + biasS[L][4 * u + 0];
                const float zi = zb[1] + biasS[L][4 * u + 1];
                const float zo = zb[2] + biasS[L][4 * u + 2];
                const float zg = zb[3] + biasS[L][4 * u + 3];
                zb[0] = 0.f; zb[1] = 0.f; zb[2] = 0.f; zb[3] = 0.f;
                const float cold = cS[L][idx];
                const float cn = sigmoidf_(zf) * cold + sigmoidf_(zi) * tanhf_(zg);
                const float hn = sigmoidf_(zo) * tanhf_(cn);
                cS[L][idx] = cn;
                hstage[L][bl][u] = __float2bfloat16(hn);
            }
        }
        __syncthreads();

        // ===== coalesced 8B bypass stores of h (straight to L3) =====
        if (tid < 256) {
            const int L  = tid >> 7;
            const int bl = tid & 127;
            const bool act = L ? (p >= 1) : (p < SEQ);
            if (act) {
                __hip_bfloat16* hw = L ? h1w : h0w;
                const u64 v = *(const u64*)&hstage[L][bl][0];
                __hip_atomic_store((u64*)(hw + (size_t)bl * HID + nb * 4), v,
                                   __ATOMIC_RELAXED, __HIP_MEMORY_SCOPE_AGENT);
            }
        }
        __syncthreads();   // every wave drains vmcnt -> stores visible at L3

        // ===== hierarchical grid barrier (bypass-atomic counters) =====
        if (tid == 0) {
            asm volatile("s_waitcnt vmcnt(0)" ::: "memory");
            int* grp = bar + 32 * (1 + (nb >> 5));
            __hip_atomic_fetch_add(grp, 1, __ATOMIC_RELAXED, __HIP_MEMORY_SCOPE_AGENT);
            if ((nb & 31) == 0) {
                const int gt = 32 * (p + 1);
                while (__hip_atomic_load(grp, __ATOMIC_RELAXED, __HIP_MEMORY_SCOPE_AGENT) < gt)
                    __builtin_amdgcn_s_sleep(1);
                __hip_atomic_fetch_add(bar, 1, __ATOMIC_RELAXED, __HIP_MEMORY_SCOPE_AGENT);
            }
            const int rt = 8 * (p + 1);
            while (__hip_atomic_load(bar, __ATOMIC_RELAXED, __HIP_MEMORY_SCOPE_AGENT) < rt)
                __builtin_amdgcn_s_sleep(1);
            if constexpr (FRESH) {
                if ((p & 31) == 31)
                    __builtin_amdgcn_fence(__ATOMIC_ACQUIRE, "agent");
            }
            asm volatile("" ::: "memory");
        }
        __syncthreads();
    }

    // ---- head: out[b] = sigmoid(h1(511) . Wout + bout) ----
    if (nb == 0 && tid < BATCH) {
        const __hip_bfloat16* hr =
            h1r + (size_t)((SEQ - 1) & RMASK) * HS + (size_t)tid * HID;
        float acc = 0.f;
        for (int k2 = 0; k2 < HID; k2 += 8) {
            bf16x8 v = FRESH ? load_bf16x8(hr + k2) : aload_bf16x8(hr + k2);
            #pragma unroll
            for (int j = 0; j < 8; ++j)
                acc += (float)v[j] * Wout[k2 + j];
        }
        out[tid] = 1.f / (1.f + __expf(-(acc + bout[0])));
    }
}

// ---------------------------------------------------------------------------
extern "C" void kernel_launch(void* const* d_in, const int* in_sizes, int n_in,
                              void* d_out, int out_size, void* d_ws, size_t ws_size,
                              hipStream_t stream)
{
    const float* x    = (const float*)d_in[0];
    const float* W0   = (const float*)d_in[1];
    const float* b0   = (const float*)d_in[2];
    const float* W1   = (const float*)d_in[3];
    const float* b1   = (const float*)d_in[4];
    const float* Wout = (const float*)d_in[5];
    const float* bout = (const float*)d_in[6];
    float* out = (float*)d_out;

    char* ws = (char*)d_ws;
    const size_t OFF_F0  = 0;            // 12,582,912
    const size_t OFF_F1  = 12582912;     // +16,777,216 -> 29,360,128
    const size_t OFF_B0R = 29360128;     // 16,384
    const size_t OFF_B1R = 29376512;     // 16,384
    const size_t OFF_BAR = 29392896;     // 4,096
    const size_t OFF_R0  = 29396992;     // rings start (4K aligned)
    const size_t SLOT    = 262144;       // one h generation: 128*1024*2B

    const size_t NEED_FRESH = OFF_R0 + 128 * SLOT;              // 62,951,424
    const bool fresh = (ws_size >= NEED_FRESH);
    const size_t OFF_R1 = fresh ? (OFF_R0 + 64 * SLOT) : (OFF_R0 + 2 * SLOT);
    const size_t OFF_XB = fresh ? NEED_FRESH : (OFF_R0 + 4 * SLOT);
    const size_t XBYTES = (size_t)BATCH * SEQ * INP * 2;        // 67,108,864
    const bool xbf = (ws_size >= OFF_XB + XBYTES);

    __hip_bfloat16* F0 = (__hip_bfloat16*)(ws + OFF_F0);
    __hip_bfloat16* F1 = (__hip_bfloat16*)(ws + OFF_F1);
    float* b0r = (float*)(ws + OFF_B0R);
    float* b1r = (float*)(ws + OFF_B1R);
    __hip_bfloat16* h0r = (__hip_bfloat16*)(ws + OFF_R0);
    __hip_bfloat16* h1r = (__hip_bfloat16*)(ws + OFF_R1);
    int* bar = (int*)(ws + OFF_BAR);
    __hip_bfloat16* xbp = (__hip_bfloat16*)(ws + OFF_XB);

    // per-call state reset (graph replays must be deterministic)
    hipMemsetAsync(ws + OFF_BAR, 0, 4096, stream);
    if (fresh) {
        hipMemsetAsync(ws + OFF_R0 + 63 * SLOT, 0, SLOT, stream);
        hipMemsetAsync(ws + OFF_R1 + 63 * SLOT, 0, SLOT, stream);
    } else {
        hipMemsetAsync(ws + OFF_R0, 0, 4 * SLOT, stream);
    }

    pack_frag_kernel<KS0><<<dim3(48, 128), 1024, 0, stream>>>(W0, F0);
    pack_frag_kernel<KS1><<<dim3(64, 128), 1024, 0, stream>>>(W1, F1);
    bias_reorder_kernel<<<32, 256, 0, stream>>>(b0, b1, b0r, b1r);
    if (xbf)
        xconv_kernel<<<(BATCH * SEQ * INP) / (256 * 8), 256, 0, stream>>>(x, xbp);

    hipFuncSetAttribute((const void*)lstm_persistent<true,  true>,
                        hipFuncAttributeMaxDynamicSharedMemorySize, LDS_DYN);
    hipFuncSetAttribute((const void*)lstm_persistent<false, true>,
                        hipFuncAttributeMaxDynamicSharedMemorySize, LDS_DYN);
    hipFuncSetAttribute((const void*)lstm_persistent<true,  false>,
                        hipFuncAttributeMaxDynamicSharedMemorySize, LDS_DYN);
    hipFuncSetAttribute((const void*)lstm_persistent<false, false>,
                        hipFuncAttributeMaxDynamicSharedMemorySize, LDS_DYN);

    void* args[] = {(void*)&x, (void*)&xbp, (void*)&F0, (void*)&F1,
                    (void*)&b0r, (void*)&b1r, (void*)&Wout, (void*)&bout,
                    (void*)&h0r, (void*)&h1r, (void*)&out, (void*)&bar};
    const void* kfun = fresh
        ? (xbf ? (const void*)lstm_persistent<true,  true>
               : (const void*)lstm_persistent<false, true>)
        : (xbf ? (const void*)lstm_persistent<true,  false>
               : (const void*)lstm_persistent<false, false>);
    hipLaunchCooperativeKernel((void*)kfun, dim3(NB), dim3(1024),
                               args, LDS_DYN, stream);
}

// Round 7
// 21093.175 us; speedup vs baseline: 1.0116x; 1.0116x over previous
//
#include <hip/hip_runtime.h>
#include <hip/hip_bf16.h>
#include <cstdint>
#include <cstddef>

// SimpleXLSTM persistent-kernel round 7.
// vs round 6: ONLY the grid barrier changed. Old: all 256 leaders spin-poll
// one root line -> ~900 bypass polls/us serialize on one L3 line (~30 us/phase).
// New: tree barrier with bounded contention -- per-group arrival lines
// (32 one-shot adds + 1 poller), root (8 adds + 1 poller, block 0), and
// 8 per-group RELEASE lines written by block 0, polled by <=32 blocks each
// with s_sleep(8) backoff. No line ever has >32 pollers.

#define BATCH 128
#define SEQ   512
#define INP   512
#define HID   1024
#define NCOL  4096
#define NB    256
#define KS0   48
#define KS1   64

typedef __bf16 bf16x8 __attribute__((ext_vector_type(8)));
typedef float  f32x4  __attribute__((ext_vector_type(4)));
typedef unsigned int u32x4 __attribute__((ext_vector_type(4)));
typedef unsigned long long u64;
typedef u64 u64x2 __attribute__((ext_vector_type(2)));

#define OFF_W0   0        // 49152
#define OFF_W1   49152    // 65536
#define LDS_DYN  114688

__device__ __forceinline__ bf16x8 load_bf16x8(const __hip_bfloat16* p) {
    u32x4 u = *reinterpret_cast<const u32x4*>(p);
    return __builtin_bit_cast(bf16x8, u);
}
__device__ __forceinline__ bf16x8 aload_bf16x8(const __hip_bfloat16* p) {
    u64x2 q;
    q[0] = __hip_atomic_load((const u64*)p,       __ATOMIC_RELAXED, __HIP_MEMORY_SCOPE_AGENT);
    q[1] = __hip_atomic_load((const u64*)(p + 4), __ATOMIC_RELAXED, __HIP_MEMORY_SCOPE_AGENT);
    return __builtin_bit_cast(bf16x8, q);
}
__device__ __forceinline__ f32x4 mfma16(bf16x8 a, bf16x8 b, f32x4 c) {
    return __builtin_amdgcn_mfma_f32_16x16x32_bf16(a, b, c, 0, 0, 0);
}
__device__ __forceinline__ float sigmoidf_(float x) {
    return 1.0f / (1.0f + __expf(-x));
}
__device__ __forceinline__ float tanhf_(float x) {
    return 1.0f - 2.0f / (__expf(2.0f * x) + 1.0f);
}

// ---------------------------------------------------------------------------
// Prep kernels (verified rounds 2-6)
// ---------------------------------------------------------------------------
template<int Ks>
__global__ __launch_bounds__(1024)
void pack_frag_kernel(const float* __restrict__ W, __hip_bfloat16* __restrict__ F)
{
    __shared__ float tile[32][33];
    const int k0 = blockIdx.x * 32;
    const int c0 = blockIdx.y * 32;
    const int tx = threadIdx.x & 31, ty = threadIdx.x >> 5;
    tile[ty][tx] = W[(size_t)(k0 + ty) * NCOL + (c0 + tx)];
    __syncthreads();
    const int cL  = threadIdx.x >> 5;
    const int kgw = (threadIdx.x >> 3) & 3;
    const int j   = threadIdx.x & 7;
    const int c   = c0 + cL;
    const int r   = (c & 1023) * 4 + (c >> 10);
    const int nb2 = r >> 4, cl = r & 15;
    const int ks  = k0 >> 5;
    const size_t chunk = ((size_t)(nb2 * Ks + ks) * 4 + kgw) * 16 + cl;
    F[chunk * 8 + j] = __float2bfloat16(tile[kgw * 8 + j][cL]);
}

__global__ void bias_reorder_kernel(const float* __restrict__ b0,
                                    const float* __restrict__ b1,
                                    float* __restrict__ b0r,
                                    float* __restrict__ b1r)
{
    int i = blockIdx.x * blockDim.x + threadIdx.x;
    if (i >= 2 * NCOL) return;
    const float* src = (i < NCOL) ? b0 : b1;
    float*       dst = (i < NCOL) ? b0r : b1r;
    int c = i & (NCOL - 1);
    dst[(c & 1023) * 4 + (c >> 10)] = src[c];
}

__global__ __launch_bounds__(256)
void xconv_kernel(const float* __restrict__ x, __hip_bfloat16* __restrict__ xb)
{
    const size_t i = ((size_t)blockIdx.x * 256 + threadIdx.x) * 8;
    f32x4 a = *(const f32x4*)(x + i);
    f32x4 b = *(const f32x4*)(x + i + 4);
    bf16x8 v;
    #pragma unroll
    for (int e = 0; e < 4; ++e) { v[e] = (__bf16)a[e]; v[e + 4] = (__bf16)b[e]; }
    *reinterpret_cast<u32x4*>((__hip_bfloat16*)xb + i) = __builtin_bit_cast(u32x4, v);
}

// ---------------------------------------------------------------------------
// Persistent kernel.  FRESH: 64-slot rings + cached h loads + periodic fence.
// ---------------------------------------------------------------------------
template<bool XBF, bool FRESH>
__global__ __launch_bounds__(1024, 4)
void lstm_persistent(const float* __restrict__ x,
                     const __hip_bfloat16* __restrict__ xb,
                     const __hip_bfloat16* __restrict__ F0,
                     const __hip_bfloat16* __restrict__ F1,
                     const float* __restrict__ b0r,
                     const float* __restrict__ b1r,
                     const float* __restrict__ Wout,
                     const float* __restrict__ bout,
                     __hip_bfloat16* __restrict__ h0r,
                     __hip_bfloat16* __restrict__ h1r,
                     float* __restrict__ out,
                     int* __restrict__ bar)
{
    constexpr int RMASK = FRESH ? 63 : 1;

    extern __shared__ char smem[];
    __hip_bfloat16* lW0 = (__hip_bfloat16*)(smem + OFF_W0);
    __hip_bfloat16* lW1 = (__hip_bfloat16*)(smem + OFF_W1);

    __shared__ float zacc[2][128][17];
    __shared__ float cS[2][512];
    __shared__ float biasS[2][16];
    __shared__ __hip_bfloat16 hstage[2][128][4];

    const int tid  = threadIdx.x;
    const int lane = tid & 63;
    const int wv   = tid >> 6;
    const int kq   = wv & 3;
    const int mq   = wv >> 2;
    const int lm   = lane & 15;
    const int kg   = lane >> 4;
    const int nb   = blockIdx.x;
    const int HS   = BATCH * HID;
    const int row0 = mq * 32 + lm;
    const int row1 = row0 + 16;

    // ---- one-time init ----
    {
        const u32x4* s0 = (const u32x4*)(F0 + (size_t)nb * (KS0 * 64 * 8));
        u32x4*       d0 = (u32x4*)lW0;
        for (int i = tid; i < KS0 * 64; i += 1024) d0[i] = s0[i];
        const u32x4* s1 = (const u32x4*)(F1 + (size_t)nb * (KS1 * 64 * 8));
        u32x4*       d1 = (u32x4*)lW1;
        for (int i = tid; i < KS1 * 64; i += 1024) d1[i] = s1[i];
        if (tid < 32) biasS[tid >> 4][tid & 15] =
            ((tid < 16) ? b0r : b1r)[nb * 16 + (tid & 15)];
        cS[tid >> 9][tid & 511] = 0.f;
        for (int i = tid; i < 2 * 128 * 17; i += 1024) ((float*)zacc)[i] = 0.f;
    }
    __syncthreads();

    for (int p = 0; p <= SEQ; ++p) {
        const __hip_bfloat16* h0prev = h0r + (size_t)((p + RMASK)     & RMASK) * HS; // h0(p-1)
        const __hip_bfloat16* h1prev = h1r + (size_t)((p + RMASK - 1) & RMASK) * HS; // h1(p-2)
        __hip_bfloat16*       h0w    = h0r + (size_t)( p              & RMASK) * HS; // h0(p)
        __hip_bfloat16*       h1w    = h1r + (size_t)((p + RMASK)     & RMASK) * HS; // h1(p-1)

        // ===== fused GEMM: layer0 (t=p) + layer1 (t=p-1), one pass =====
        {
            f32x4 aL0r0 = {0,0,0,0}, aL0r1 = {0,0,0,0};
            f32x4 aL1r0 = {0,0,0,0}, aL1r1 = {0,0,0,0};
            bf16x8 A0s[4], A1s[4], B0s[4], B1s[4];

            const size_t xoff = (size_t)(p < SEQ ? p : 0) * INP;
            const __hip_bfloat16* hr0 = h0prev + (size_t)row0 * HID;
            const __hip_bfloat16* hr1 = h0prev + (size_t)row1 * HID;
            const __hip_bfloat16* qr0 = h1prev + (size_t)row0 * HID;
            const __hip_bfloat16* qr1 = h1prev + (size_t)row1 * HID;

            auto loadU = [&](int u, int s) {
                if (u < 4) {
                    const int ks = kq + 4 * u;
                    const int k  = ks * 32 + kg * 8;
                    B0s[s] = *(const bf16x8*)(lW0 + (size_t)(((ks * 4 + kg) * 16 + lm) * 8));
                    if constexpr (XBF) {
                        A0s[s] = load_bf16x8(xb + (size_t)row0 * (SEQ * INP) + xoff + k);
                        A1s[s] = load_bf16x8(xb + (size_t)row1 * (SEQ * INP) + xoff + k);
                    } else {
                        const float* p0 = x + (size_t)row0 * (SEQ * INP) + xoff + k;
                        const float* p1 = x + (size_t)row1 * (SEQ * INP) + xoff + k;
                        f32x4 a = *(const f32x4*)p0, b = *(const f32x4*)(p0 + 4);
                        f32x4 c = *(const f32x4*)p1, d = *(const f32x4*)(p1 + 4);
                        bf16x8 v0, v1;
                        #pragma unroll
                        for (int e = 0; e < 4; ++e) {
                            v0[e] = (__bf16)a[e]; v0[e + 4] = (__bf16)b[e];
                            v1[e] = (__bf16)c[e]; v1[e + 4] = (__bf16)d[e];
                        }
                        A0s[s] = v0; A1s[s] = v1;
                    }
                } else if (u < 12) {
                    const int ksh = kq + 4 * (u - 4);
                    const int k   = ksh * 32 + kg * 8;
                    B0s[s] = *(const bf16x8*)(lW0 + (size_t)((((16 + ksh) * 4 + kg) * 16 + lm) * 8));
                    B1s[s] = *(const bf16x8*)(lW1 + (size_t)(((ksh * 4 + kg) * 16 + lm) * 8));
                    if constexpr (FRESH) {
                        A0s[s] = load_bf16x8(hr0 + k);
                        A1s[s] = load_bf16x8(hr1 + k);
                    } else {
                        A0s[s] = aload_bf16x8(hr0 + k);
                        A1s[s] = aload_bf16x8(hr1 + k);
                    }
                } else {
                    const int ksq = kq + 4 * (u - 12);
                    const int k   = ksq * 32 + kg * 8;
                    B1s[s] = *(const bf16x8*)(lW1 + (size_t)((((32 + ksq) * 4 + kg) * 16 + lm) * 8));
                    if constexpr (FRESH) {
                        A0s[s] = load_bf16x8(qr0 + k);
                        A1s[s] = load_bf16x8(qr1 + k);
                    } else {
                        A0s[s] = aload_bf16x8(qr0 + k);
                        A1s[s] = aload_bf16x8(qr1 + k);
                    }
                }
            };

            #pragma unroll
            for (int u = 0; u < 4; ++u) loadU(u, u);
            #pragma unroll
            for (int u = 0; u < 20; ++u) {
                const int s = u & 3;
                if (u < 12) {
                    aL0r0 = mfma16(A0s[s], B0s[s], aL0r0);
                    aL0r1 = mfma16(A1s[s], B0s[s], aL0r1);
                }
                if (u >= 4) {
                    aL1r0 = mfma16(A0s[s], B1s[s], aL1r0);
                    aL1r1 = mfma16(A1s[s], B1s[s], aL1r1);
                }
                if (u < 16) loadU(u + 4, s);
            }

            if (p < SEQ) {
                #pragma unroll
                for (int r = 0; r < 4; ++r) {
                    atomicAdd(&zacc[0][mq * 32 + kg * 4 + r][lm],      aL0r0[r]);
                    atomicAdd(&zacc[0][mq * 32 + 16 + kg * 4 + r][lm], aL0r1[r]);
                }
            }
            if (p >= 1) {
                #pragma unroll
                for (int r = 0; r < 4; ++r) {
                    atomicAdd(&zacc[1][mq * 32 + kg * 4 + r][lm],      aL1r0[r]);
                    atomicAdd(&zacc[1][mq * 32 + 16 + kg * 4 + r][lm], aL1r1[r]);
                }
            }
        }
        __syncthreads();

        // ===== gates -> hstage (LDS) =====
        {
            const int L   = tid >> 9;
            const int idx = tid & 511;
            const int bl  = idx >> 2;
            const int u   = idx & 3;
            const bool act = L ? (p >= 1) : (p < SEQ);
            if (act) {
                float* zb = &zacc[L][bl][4 * u];
                const float zf = zb[0] + biasS[L][4 * u + 0];
                const float zi = zb[1] + biasS[L][4 * u + 1];
                const float zo = zb[2] + biasS[L][4 * u + 2];
                const float zg = zb[3] + biasS[L][4 * u + 3];
                zb[0] = 0.f; zb[1] = 0.f; zb[2] = 0.f; zb[3] = 0.f;
                const float cold = cS[L][idx];
                const float cn = sigmoidf_(zf) * cold + sigmoidf_(zi) * tanhf_(zg);
                const float hn = sigmoidf_(zo) * tanhf_(cn);
                cS[L][idx] = cn;
                hstage[L][bl][u] = __float2bfloat16(hn);
            }
        }
        __syncthreads();

        // ===== coalesced 8B bypass stores of h (straight to L3) =====
        if (tid < 256) {
            const int L  = tid >> 7;
            const int bl = tid & 127;
            const bool act = L ? (p >= 1) : (p < SEQ);
            if (act) {
                __hip_bfloat16* hw = L ? h1w : h0w;
                const u64 v = *(const u64*)&hstage[L][bl][0];
                __hip_atomic_store((u64*)(hw + (size_t)bl * HID + nb * 4), v,
                                   __ATOMIC_RELAXED, __HIP_MEMORY_SCOPE_AGENT);
            }
        }
        __syncthreads();   // storing waves drain vmcnt -> stores visible at L3

        // ===== low-contention tree barrier =====
        // lines (128B apart): arrival[g]=bar+32g, root=bar+256, release[g]=bar+512+32g
        if (tid == 0) {
            asm volatile("s_waitcnt vmcnt(0)" ::: "memory");
            const int g = nb >> 5;
            int* arrv = bar + 32 * g;
            int* root = bar + 256;
            int* rel  = bar + 512 + 32 * g;
            const int e = p + 1;
            __hip_atomic_fetch_add(arrv, 1, __ATOMIC_RELAXED, __HIP_MEMORY_SCOPE_AGENT);
            if ((nb & 31) == 0) {
                while (__hip_atomic_load(arrv, __ATOMIC_RELAXED, __HIP_MEMORY_SCOPE_AGENT) < 32 * e)
                    __builtin_amdgcn_s_sleep(2);
                __hip_atomic_fetch_add(root, 1, __ATOMIC_RELAXED, __HIP_MEMORY_SCOPE_AGENT);
            }
            if (nb == 0) {
                while (__hip_atomic_load(root, __ATOMIC_RELAXED, __HIP_MEMORY_SCOPE_AGENT) < 8 * e)
                    __builtin_amdgcn_s_sleep(2);
                #pragma unroll
                for (int gg = 0; gg < 8; ++gg)
                    __hip_atomic_store(bar + 512 + 32 * gg, e,
                                       __ATOMIC_RELAXED, __HIP_MEMORY_SCOPE_AGENT);
            } else {
                while (__hip_atomic_load(rel, __ATOMIC_RELAXED, __HIP_MEMORY_SCOPE_AGENT) < e)
                    __builtin_amdgcn_s_sleep(8);
            }
            if constexpr (FRESH) {
                if ((p & 31) == 31)
                    __builtin_amdgcn_fence(__ATOMIC_ACQUIRE, "agent");
            }
            asm volatile("" ::: "memory");
        }
        __syncthreads();
    }

    // ---- head: out[b] = sigmoid(h1(511) . Wout + bout) ----
    if (nb == 0 && tid < BATCH) {
        const __hip_bfloat16* hr =
            h1r + (size_t)((SEQ - 1) & RMASK) * HS + (size_t)tid * HID;
        float acc = 0.f;
        for (int k2 = 0; k2 < HID; k2 += 8) {
            bf16x8 v = FRESH ? load_bf16x8(hr + k2) : aload_bf16x8(hr + k2);
            #pragma unroll
            for (int j = 0; j < 8; ++j)
                acc += (float)v[j] * Wout[k2 + j];
        }
        out[tid] = 1.f / (1.f + __expf(-(acc + bout[0])));
    }
}

// ---------------------------------------------------------------------------
extern "C" void kernel_launch(void* const* d_in, const int* in_sizes, int n_in,
                              void* d_out, int out_size, void* d_ws, size_t ws_size,
                              hipStream_t stream)
{
    const float* x    = (const float*)d_in[0];
    const float* W0   = (const float*)d_in[1];
    const float* b0   = (const float*)d_in[2];
    const float* W1   = (const float*)d_in[3];
    const float* b1   = (const float*)d_in[4];
    const float* Wout = (const float*)d_in[5];
    const float* bout = (const float*)d_in[6];
    float* out = (float*)d_out;

    char* ws = (char*)d_ws;
    const size_t OFF_F0  = 0;            // 12,582,912
    const size_t OFF_F1  = 12582912;     // +16,777,216 -> 29,360,128
    const size_t OFF_B0R = 29360128;     // 16,384
    const size_t OFF_B1R = 29376512;     // 16,384
    const size_t OFF_BAR = 29392896;     // 4,096
    const size_t OFF_R0  = 29396992;     // rings start
    const size_t SLOT    = 262144;       // one h generation: 128*1024*2B

    const size_t NEED_FRESH = OFF_R0 + 128 * SLOT;
    const bool fresh = (ws_size >= NEED_FRESH);
    const size_t OFF_R1 = fresh ? (OFF_R0 + 64 * SLOT) : (OFF_R0 + 2 * SLOT);
    const size_t OFF_XB = fresh ? NEED_FRESH : (OFF_R0 + 4 * SLOT);
    const size_t XBYTES = (size_t)BATCH * SEQ * INP * 2;
    const bool xbf = (ws_size >= OFF_XB + XBYTES);

    __hip_bfloat16* F0 = (__hip_bfloat16*)(ws + OFF_F0);
    __hip_bfloat16* F1 = (__hip_bfloat16*)(ws + OFF_F1);
    float* b0r = (float*)(ws + OFF_B0R);
    float* b1r = (float*)(ws + OFF_B1R);
    __hip_bfloat16* h0r = (__hip_bfloat16*)(ws + OFF_R0);
    __hip_bfloat16* h1r = (__hip_bfloat16*)(ws + OFF_R1);
    int* bar = (int*)(ws + OFF_BAR);
    __hip_bfloat16* xbp = (__hip_bfloat16*)(ws + OFF_XB);

    // per-call state reset (graph replays must be deterministic)
    hipMemsetAsync(ws + OFF_BAR, 0, 4096, stream);
    if (fresh) {
        hipMemsetAsync(ws + OFF_R0 + 63 * SLOT, 0, SLOT, stream);
        hipMemsetAsync(ws + OFF_R1 + 63 * SLOT, 0, SLOT, stream);
    } else {
        hipMemsetAsync(ws + OFF_R0, 0, 4 * SLOT, stream);
    }

    pack_frag_kernel<KS0><<<dim3(48, 128), 1024, 0, stream>>>(W0, F0);
    pack_frag_kernel<KS1><<<dim3(64, 128), 1024, 0, stream>>>(W1, F1);
    bias_reorder_kernel<<<32, 256, 0, stream>>>(b0, b1, b0r, b1r);
    if (xbf)
        xconv_kernel<<<(BATCH * SEQ * INP) / (256 * 8), 256, 0, stream>>>(x, xbp);

    hipFuncSetAttribute((const void*)lstm_persistent<true,  true>,
                        hipFuncAttributeMaxDynamicSharedMemorySize, LDS_DYN);
    hipFuncSetAttribute((const void*)lstm_persistent<false, true>,
                        hipFuncAttributeMaxDynamicSharedMemorySize, LDS_DYN);
    hipFuncSetAttribute((const void*)lstm_persistent<true,  false>,
                        hipFuncAttributeMaxDynamicSharedMemorySize, LDS_DYN);
    hipFuncSetAttribute((const void*)lstm_persistent<false, false>,
                        hipFuncAttributeMaxDynamicSharedMemorySize, LDS_DYN);

    void* args[] = {(void*)&x, (void*)&xbp, (void*)&F0, (void*)&F1,
                    (void*)&b0r, (void*)&b1r, (void*)&Wout, (void*)&bout,
                    (void*)&h0r, (void*)&h1r, (void*)&out, (void*)&bar};
    const void* kfun = fresh
        ? (xbf ? (const void*)lstm_persistent<true,  true>
               : (const void*)lstm_persistent<false, true>)
        : (xbf ? (const void*)lstm_persistent<true,  false>
               : (const void*)lstm_persistent<false, false>);
    hipLaunchCooperativeKernel((void*)kfun, dim3(NB), dim3(1024),
                               args, LDS_DYN, stream);
}

// Round 8
// 16802.867 us; speedup vs baseline: 1.2699x; 1.2553x over previous
//
#include <hip/hip_runtime.h>
#include <hip/hip_bf16.h>
#include <cstdint>
#include <cstddef>

// SimpleXLSTM persistent-kernel round 8.
// vs round 7: the GEMM k-loop is restructured into 5 groups of 4 k-steps with
// an explicit issue(g+1) -> sched_barrier(0) -> compute(g) double-buffered
// pipeline (compiler provably never built the prefetch ring: VGPR=48..52 in
// r5-r7). x-section loads for phase p+1 are issued before a RAW s_barrier
// (no vmcnt drain) so they fly across the grid barrier. Rings / tree barrier
// unchanged (verified absmax 0.0 rounds 5-7).

#define BATCH 128
#define SEQ   512
#define INP   512
#define HID   1024
#define NCOL  4096
#define NB    256
#define KS0   48
#define KS1   64

typedef __bf16 bf16x8 __attribute__((ext_vector_type(8)));
typedef float  f32x4  __attribute__((ext_vector_type(4)));
typedef unsigned int u32x4 __attribute__((ext_vector_type(4)));
typedef unsigned long long u64;
typedef u64 u64x2 __attribute__((ext_vector_type(2)));

#define OFF_W0   0        // 49152
#define OFF_W1   49152    // 65536
#define LDS_DYN  114688

__device__ __forceinline__ bf16x8 load_bf16x8(const __hip_bfloat16* p) {
    u32x4 u = *reinterpret_cast<const u32x4*>(p);
    return __builtin_bit_cast(bf16x8, u);
}
__device__ __forceinline__ bf16x8 aload_bf16x8(const __hip_bfloat16* p) {
    u64x2 q;
    q[0] = __hip_atomic_load((const u64*)p,       __ATOMIC_RELAXED, __HIP_MEMORY_SCOPE_AGENT);
    q[1] = __hip_atomic_load((const u64*)(p + 4), __ATOMIC_RELAXED, __HIP_MEMORY_SCOPE_AGENT);
    return __builtin_bit_cast(bf16x8, q);
}
__device__ __forceinline__ f32x4 mfma16(bf16x8 a, bf16x8 b, f32x4 c) {
    return __builtin_amdgcn_mfma_f32_16x16x32_bf16(a, b, c, 0, 0, 0);
}
__device__ __forceinline__ float sigmoidf_(float x) {
    return 1.0f / (1.0f + __expf(-x));
}
__device__ __forceinline__ float tanhf_(float x) {
    return 1.0f - 2.0f / (__expf(2.0f * x) + 1.0f);
}

// ---------------------------------------------------------------------------
// Prep kernels (verified rounds 2-7)
// ---------------------------------------------------------------------------
template<int Ks>
__global__ __launch_bounds__(1024)
void pack_frag_kernel(const float* __restrict__ W, __hip_bfloat16* __restrict__ F)
{
    __shared__ float tile[32][33];
    const int k0 = blockIdx.x * 32;
    const int c0 = blockIdx.y * 32;
    const int tx = threadIdx.x & 31, ty = threadIdx.x >> 5;
    tile[ty][tx] = W[(size_t)(k0 + ty) * NCOL + (c0 + tx)];
    __syncthreads();
    const int cL  = threadIdx.x >> 5;
    const int kgw = (threadIdx.x >> 3) & 3;
    const int j   = threadIdx.x & 7;
    const int c   = c0 + cL;
    const int r   = (c & 1023) * 4 + (c >> 10);
    const int nb2 = r >> 4, cl = r & 15;
    const int ks  = k0 >> 5;
    const size_t chunk = ((size_t)(nb2 * Ks + ks) * 4 + kgw) * 16 + cl;
    F[chunk * 8 + j] = __float2bfloat16(tile[kgw * 8 + j][cL]);
}

__global__ void bias_reorder_kernel(const float* __restrict__ b0,
                                    const float* __restrict__ b1,
                                    float* __restrict__ b0r,
                                    float* __restrict__ b1r)
{
    int i = blockIdx.x * blockDim.x + threadIdx.x;
    if (i >= 2 * NCOL) return;
    const float* src = (i < NCOL) ? b0 : b1;
    float*       dst = (i < NCOL) ? b0r : b1r;
    int c = i & (NCOL - 1);
    dst[(c & 1023) * 4 + (c >> 10)] = src[c];
}

__global__ __launch_bounds__(256)
void xconv_kernel(const float* __restrict__ x, __hip_bfloat16* __restrict__ xb)
{
    const size_t i = ((size_t)blockIdx.x * 256 + threadIdx.x) * 8;
    f32x4 a = *(const f32x4*)(x + i);
    f32x4 b = *(const f32x4*)(x + i + 4);
    bf16x8 v;
    #pragma unroll
    for (int e = 0; e < 4; ++e) { v[e] = (__bf16)a[e]; v[e + 4] = (__bf16)b[e]; }
    *reinterpret_cast<u32x4*>((__hip_bfloat16*)xb + i) = __builtin_bit_cast(u32x4, v);
}

// ---------------------------------------------------------------------------
template<bool XBF, bool FRESH>
__global__ __launch_bounds__(1024, 4)
void lstm_persistent(const float* __restrict__ x,
                     const __hip_bfloat16* __restrict__ xb,
                     const __hip_bfloat16* __restrict__ F0,
                     const __hip_bfloat16* __restrict__ F1,
                     const float* __restrict__ b0r,
                     const float* __restrict__ b1r,
                     const float* __restrict__ Wout,
                     const float* __restrict__ bout,
                     __hip_bfloat16* __restrict__ h0r,
                     __hip_bfloat16* __restrict__ h1r,
                     float* __restrict__ out,
                     int* __restrict__ bar)
{
    constexpr int RMASK = FRESH ? 63 : 1;

    extern __shared__ char smem[];
    __hip_bfloat16* lW0 = (__hip_bfloat16*)(smem + OFF_W0);
    __hip_bfloat16* lW1 = (__hip_bfloat16*)(smem + OFF_W1);

    __shared__ float zacc[2][128][17];
    __shared__ float cS[2][512];
    __shared__ float biasS[2][16];
    __shared__ __hip_bfloat16 hstage[2][128][4];

    const int tid  = threadIdx.x;
    const int lane = tid & 63;
    const int wv   = tid >> 6;
    const int kq   = wv & 3;
    const int mq   = wv >> 2;
    const int lm   = lane & 15;
    const int kg   = lane >> 4;
    const int nb   = blockIdx.x;
    const int HS   = BATCH * HID;
    const int row0 = mq * 32 + lm;
    const int row1 = row0 + 16;

    // ---- one-time init ----
    {
        const u32x4* s0 = (const u32x4*)(F0 + (size_t)nb * (KS0 * 64 * 8));
        u32x4*       d0 = (u32x4*)lW0;
        for (int i = tid; i < KS0 * 64; i += 1024) d0[i] = s0[i];
        const u32x4* s1 = (const u32x4*)(F1 + (size_t)nb * (KS1 * 64 * 8));
        u32x4*       d1 = (u32x4*)lW1;
        for (int i = tid; i < KS1 * 64; i += 1024) d1[i] = s1[i];
        if (tid < 32) biasS[tid >> 4][tid & 15] =
            ((tid < 16) ? b0r : b1r)[nb * 16 + (tid & 15)];
        cS[tid >> 9][tid & 511] = 0.f;
        for (int i = tid; i < 2 * 128 * 17; i += 1024) ((float*)zacc)[i] = 0.f;
    }
    __syncthreads();

    // persistent A-fragment double buffers (all indices static after unroll)
    bf16x8 A0a[4], A1a[4], A0b[4], A1b[4];

    // ---- group issue/compute helpers ----
    auto issueG0 = [&](int p_) {  // x section -> a-buffers
        const size_t xoff = (size_t)(p_ < SEQ ? p_ : 0) * INP;
        #pragma unroll
        for (int i = 0; i < 4; ++i) {
            const int ks = kq + 4 * i;
            const int k  = ks * 32 + kg * 8;
            if constexpr (XBF) {
                A0a[i] = load_bf16x8(xb + (size_t)row0 * (SEQ * INP) + xoff + k);
                A1a[i] = load_bf16x8(xb + (size_t)row1 * (SEQ * INP) + xoff + k);
            } else {
                const float* p0 = x + (size_t)row0 * (SEQ * INP) + xoff + k;
                const float* p1 = x + (size_t)row1 * (SEQ * INP) + xoff + k;
                f32x4 a = *(const f32x4*)p0, b = *(const f32x4*)(p0 + 4);
                f32x4 c = *(const f32x4*)p1, d = *(const f32x4*)(p1 + 4);
                bf16x8 v0, v1;
                #pragma unroll
                for (int e = 0; e < 4; ++e) {
                    v0[e] = (__bf16)a[e]; v0[e + 4] = (__bf16)b[e];
                    v1[e] = (__bf16)c[e]; v1[e + 4] = (__bf16)d[e];
                }
                A0a[i] = v0; A1a[i] = v1;
            }
        }
    };
    auto issueH = [&](const __hip_bfloat16* r0p, const __hip_bfloat16* r1p,
                      int base, bf16x8 (&A0)[4], bf16x8 (&A1)[4]) {
        #pragma unroll
        for (int i = 0; i < 4; ++i) {
            const int ks = kq + 4 * (base + i);
            const int k  = ks * 32 + kg * 8;
            if constexpr (FRESH) {
                A0[i] = load_bf16x8(r0p + k);
                A1[i] = load_bf16x8(r1p + k);
            } else {
                A0[i] = aload_bf16x8(r0p + k);
                A1[i] = aload_bf16x8(r1p + k);
            }
        }
    };
    auto computeG0 = [&](f32x4& c0, f32x4& c1) {
        #pragma unroll
        for (int i = 0; i < 4; ++i) {
            const int ks = kq + 4 * i;
            bf16x8 B = *(const bf16x8*)(lW0 + (size_t)(((ks * 4 + kg) * 16 + lm) * 8));
            c0 = mfma16(A0a[i], B, c0);
            c1 = mfma16(A1a[i], B, c1);
        }
    };
    auto computeH0 = [&](int base, bf16x8 (&A0)[4], bf16x8 (&A1)[4],
                         f32x4& l00, f32x4& l01, f32x4& l10, f32x4& l11) {
        #pragma unroll
        for (int i = 0; i < 4; ++i) {
            const int ksh = kq + 4 * (base + i);
            bf16x8 B0 = *(const bf16x8*)(lW0 + (size_t)((((16 + ksh) * 4 + kg) * 16 + lm) * 8));
            bf16x8 B1 = *(const bf16x8*)(lW1 + (size_t)(((ksh * 4 + kg) * 16 + lm) * 8));
            l00 = mfma16(A0[i], B0, l00);
            l01 = mfma16(A1[i], B0, l01);
            l10 = mfma16(A0[i], B1, l10);
            l11 = mfma16(A1[i], B1, l11);
        }
    };
    auto computeH1 = [&](int base, bf16x8 (&A0)[4], bf16x8 (&A1)[4],
                         f32x4& c0, f32x4& c1) {
        #pragma unroll
        for (int i = 0; i < 4; ++i) {
            const int ksq = kq + 4 * (base + i);
            bf16x8 B = *(const bf16x8*)(lW1 + (size_t)((((32 + ksq) * 4 + kg) * 16 + lm) * 8));
            c0 = mfma16(A0[i], B, c0);
            c1 = mfma16(A1[i], B, c1);
        }
    };

    if constexpr (XBF) issueG0(0);   // prologue prefetch of phase-0 x

    for (int p = 0; p <= SEQ; ++p) {
        const __hip_bfloat16* h0prev = h0r + (size_t)((p + RMASK)     & RMASK) * HS;
        const __hip_bfloat16* h1prev = h1r + (size_t)((p + RMASK - 1) & RMASK) * HS;
        __hip_bfloat16*       h0w    = h0r + (size_t)( p              & RMASK) * HS;
        __hip_bfloat16*       h1w    = h1r + (size_t)((p + RMASK)     & RMASK) * HS;

        const __hip_bfloat16* hr0 = h0prev + (size_t)row0 * HID;
        const __hip_bfloat16* hr1 = h0prev + (size_t)row1 * HID;
        const __hip_bfloat16* qr0 = h1prev + (size_t)row0 * HID;
        const __hip_bfloat16* qr1 = h1prev + (size_t)row1 * HID;

        // ===== pipelined fused GEMM: 5 groups, issue(g+1) || compute(g) =====
        {
            f32x4 aL0r0 = {0,0,0,0}, aL0r1 = {0,0,0,0};
            f32x4 aL1r0 = {0,0,0,0}, aL1r1 = {0,0,0,0};

            issueH(hr0, hr1, 0, A0b, A1b);              // G1 (h0 a) -> b
            if constexpr (!XBF) issueG0(p);             // (fp32 path: head issue)
            __builtin_amdgcn_sched_barrier(0);
            computeG0(aL0r0, aL0r1);                    // G0 from a

            issueH(hr0, hr1, 4, A0a, A1a);              // G2 (h0 b) -> a
            __builtin_amdgcn_sched_barrier(0);
            computeH0(0, A0b, A1b, aL0r0, aL0r1, aL1r0, aL1r1);   // G1

            issueH(qr0, qr1, 0, A0b, A1b);              // G3 (h1 a) -> b
            __builtin_amdgcn_sched_barrier(0);
            computeH0(4, A0a, A1a, aL0r0, aL0r1, aL1r0, aL1r1);   // G2

            issueH(qr0, qr1, 4, A0a, A1a);              // G4 (h1 b) -> a
            __builtin_amdgcn_sched_barrier(0);
            computeH1(0, A0b, A1b, aL1r0, aL1r1);       // G3
            __builtin_amdgcn_sched_barrier(0);
            computeH1(4, A0a, A1a, aL1r0, aL1r1);       // G4

            if (p < SEQ) {
                #pragma unroll
                for (int r = 0; r < 4; ++r) {
                    atomicAdd(&zacc[0][mq * 32 + kg * 4 + r][lm],      aL0r0[r]);
                    atomicAdd(&zacc[0][mq * 32 + 16 + kg * 4 + r][lm], aL0r1[r]);
                }
            }
            if (p >= 1) {
                #pragma unroll
                for (int r = 0; r < 4; ++r) {
                    atomicAdd(&zacc[1][mq * 32 + kg * 4 + r][lm],      aL1r0[r]);
                    atomicAdd(&zacc[1][mq * 32 + 16 + kg * 4 + r][lm], aL1r1[r]);
                }
            }
        }
        __syncthreads();

        // ===== gates -> hstage (LDS) =====
        {
            const int L   = tid >> 9;
            const int idx = tid & 511;
            const int bl  = idx >> 2;
            const int u   = idx & 3;
            const bool act = L ? (p >= 1) : (p < SEQ);
            if (act) {
                float* zb = &zacc[L][bl][4 * u];
                const float zf = zb[0] + biasS[L][4 * u + 0];
                const float zi = zb[1] + biasS[L][4 * u + 1];
                const float zo = zb[2] + biasS[L][4 * u + 2];
                const float zg = zb[3] + biasS[L][4 * u + 3];
                zb[0] = 0.f; zb[1] = 0.f; zb[2] = 0.f; zb[3] = 0.f;
                const float cold = cS[L][idx];
                const float cn = sigmoidf_(zf) * cold + sigmoidf_(zi) * tanhf_(zg);
                const float hn = sigmoidf_(zo) * tanhf_(cn);
                cS[L][idx] = cn;
                hstage[L][bl][u] = __float2bfloat16(hn);
            }
        }
        __syncthreads();

        // ===== coalesced 8B bypass stores of h (straight to L3) =====
        if (tid < 256) {
            const int L  = tid >> 7;
            const int bl = tid & 127;
            const bool act = L ? (p >= 1) : (p < SEQ);
            if (act) {
                __hip_bfloat16* hw = L ? h1w : h0w;
                const u64 v = *(const u64*)&hstage[L][bl][0];
                __hip_atomic_store((u64*)(hw + (size_t)bl * HID + nb * 4), v,
                                   __ATOMIC_RELAXED, __HIP_MEMORY_SCOPE_AGENT);
            }
        }
        __syncthreads();   // drains every wave's store vmcnt -> visible at L3

        // ===== cross-barrier x-prefetch for phase p+1 (h-independent) =====
        if constexpr (XBF) {
            if (p < SEQ) issueG0(p + 1);
            __builtin_amdgcn_sched_barrier(0);
        }

        // ===== low-contention tree barrier (no vmcnt drain needed here:
        //       the post-store __syncthreads already drained every wave) =====
        if (tid == 0) {
            const int g = nb >> 5;
            int* arrv = bar + 32 * g;
            int* root = bar + 256;
            int* rel  = bar + 512 + 32 * g;
            const int e = p + 1;
            __hip_atomic_fetch_add(arrv, 1, __ATOMIC_RELAXED, __HIP_MEMORY_SCOPE_AGENT);
            if ((nb & 31) == 0) {
                while (__hip_atomic_load(arrv, __ATOMIC_RELAXED, __HIP_MEMORY_SCOPE_AGENT) < 32 * e)
                    __builtin_amdgcn_s_sleep(1);
                __hip_atomic_fetch_add(root, 1, __ATOMIC_RELAXED, __HIP_MEMORY_SCOPE_AGENT);
            }
            if (nb == 0) {
                while (__hip_atomic_load(root, __ATOMIC_RELAXED, __HIP_MEMORY_SCOPE_AGENT) < 8 * e)
                    __builtin_amdgcn_s_sleep(1);
                #pragma unroll
                for (int gg = 0; gg < 8; ++gg)
                    __hip_atomic_store(bar + 512 + 32 * gg, e,
                                       __ATOMIC_RELAXED, __HIP_MEMORY_SCOPE_AGENT);
            } else {
                while (__hip_atomic_load(rel, __ATOMIC_RELAXED, __HIP_MEMORY_SCOPE_AGENT) < e)
                    __builtin_amdgcn_s_sleep(2);
            }
            if constexpr (FRESH) {
                if ((p & 31) == 31)
                    __builtin_amdgcn_fence(__ATOMIC_ACQUIRE, "agent");
            }
            asm volatile("" ::: "memory");
        }
        // RAW barrier: no compiler-inserted vmcnt drain -> x-prefetch stays
        // in flight across the grid barrier. No memory handoff crosses this
        // point that isn't already L3-visible (stores drained 2 barriers ago).
        __builtin_amdgcn_s_barrier();
    }

    // ---- head: out[b] = sigmoid(h1(511) . Wout + bout) ----
    if (nb == 0 && tid < BATCH) {
        const __hip_bfloat16* hr =
            h1r + (size_t)((SEQ - 1) & RMASK) * HS + (size_t)tid * HID;
        float acc = 0.f;
        for (int k2 = 0; k2 < HID; k2 += 8) {
            bf16x8 v = FRESH ? load_bf16x8(hr + k2) : aload_bf16x8(hr + k2);
            #pragma unroll
            for (int j = 0; j < 8; ++j)
                acc += (float)v[j] * Wout[k2 + j];
        }
        out[tid] = 1.f / (1.f + __expf(-(acc + bout[0])));
    }
}

// ---------------------------------------------------------------------------
extern "C" void kernel_launch(void* const* d_in, const int* in_sizes, int n_in,
                              void* d_out, int out_size, void* d_ws, size_t ws_size,
                              hipStream_t stream)
{
    const float* x    = (const float*)d_in[0];
    const float* W0   = (const float*)d_in[1];
    const float* b0   = (const float*)d_in[2];
    const float* W1   = (const float*)d_in[3];
    const float* b1   = (const float*)d_in[4];
    const float* Wout = (const float*)d_in[5];
    const float* bout = (const float*)d_in[6];
    float* out = (float*)d_out;

    char* ws = (char*)d_ws;
    const size_t OFF_F0  = 0;            // 12,582,912
    const size_t OFF_F1  = 12582912;     // +16,777,216 -> 29,360,128
    const size_t OFF_B0R = 29360128;     // 16,384
    const size_t OFF_B1R = 29376512;     // 16,384
    const size_t OFF_BAR = 29392896;     // 4,096
    const size_t OFF_R0  = 29396992;     // rings start
    const size_t SLOT    = 262144;       // one h generation: 128*1024*2B

    const size_t NEED_FRESH = OFF_R0 + 128 * SLOT;
    const bool fresh = (ws_size >= NEED_FRESH);
    const size_t OFF_R1 = fresh ? (OFF_R0 + 64 * SLOT) : (OFF_R0 + 2 * SLOT);
    const size_t OFF_XB = fresh ? NEED_FRESH : (OFF_R0 + 4 * SLOT);
    const size_t XBYTES = (size_t)BATCH * SEQ * INP * 2;
    const bool xbf = (ws_size >= OFF_XB + XBYTES);

    __hip_bfloat16* F0 = (__hip_bfloat16*)(ws + OFF_F0);
    __hip_bfloat16* F1 = (__hip_bfloat16*)(ws + OFF_F1);
    float* b0r = (float*)(ws + OFF_B0R);
    float* b1r = (float*)(ws + OFF_B1R);
    __hip_bfloat16* h0r = (__hip_bfloat16*)(ws + OFF_R0);
    __hip_bfloat16* h1r = (__hip_bfloat16*)(ws + OFF_R1);
    int* bar = (int*)(ws + OFF_BAR);
    __hip_bfloat16* xbp = (__hip_bfloat16*)(ws + OFF_XB);

    // per-call state reset (graph replays must be deterministic)
    hipMemsetAsync(ws + OFF_BAR, 0, 4096, stream);
    if (fresh) {
        hipMemsetAsync(ws + OFF_R0 + 63 * SLOT, 0, SLOT, stream);
        hipMemsetAsync(ws + OFF_R1 + 63 * SLOT, 0, SLOT, stream);
    } else {
        hipMemsetAsync(ws + OFF_R0, 0, 4 * SLOT, stream);
    }

    pack_frag_kernel<KS0><<<dim3(48, 128), 1024, 0, stream>>>(W0, F0);
    pack_frag_kernel<KS1><<<dim3(64, 128), 1024, 0, stream>>>(W1, F1);
    bias_reorder_kernel<<<32, 256, 0, stream>>>(b0, b1, b0r, b1r);
    if (xbf)
        xconv_kernel<<<(BATCH * SEQ * INP) / (256 * 8), 256, 0, stream>>>(x, xbp);

    hipFuncSetAttribute((const void*)lstm_persistent<true,  true>,
                        hipFuncAttributeMaxDynamicSharedMemorySize, LDS_DYN);
    hipFuncSetAttribute((const void*)lstm_persistent<false, true>,
                        hipFuncAttributeMaxDynamicSharedMemorySize, LDS_DYN);
    hipFuncSetAttribute((const void*)lstm_persistent<true,  false>,
                        hipFuncAttributeMaxDynamicSharedMemorySize, LDS_DYN);
    hipFuncSetAttribute((const void*)lstm_persistent<false, false>,
                        hipFuncAttributeMaxDynamicSharedMemorySize, LDS_DYN);

    void* args[] = {(void*)&x, (void*)&xbp, (void*)&F0, (void*)&F1,
                    (void*)&b0r, (void*)&b1r, (void*)&Wout, (void*)&bout,
                    (void*)&h0r, (void*)&h1r, (void*)&out, (void*)&bar};
    const void* kfun = fresh
        ? (xbf ? (const void*)lstm_persistent<true,  true>
               : (const void*)lstm_persistent<false, true>)
        : (xbf ? (const void*)lstm_persistent<true,  false>
               : (const void*)lstm_persistent<false, false>);
    hipLaunchCooperativeKernel((void*)kfun, dim3(NB), dim3(1024),
                               args, LDS_DYN, stream);
}

// Round 9
// 15279.333 us; speedup vs baseline: 1.3966x; 1.0997x over previous
//
#include <hip/hip_runtime.h>
#include <hip/hip_bf16.h>
#include <cstdint>
#include <cstddef>

// SimpleXLSTM persistent-kernel round 9.
// Core change: A-operands staged via global_load_lds into per-wave private
// 4-slot LDS rings with counted vmcnt(12) (3 steps = 12 KB in flight/wave,
// ~96 KB/CU vs ~1.5 KB in rounds 5-8 -> latency fully hidden). Weights move
// from LDS to VGPRs (112/wave, phase-invariant) to free the LDS. 8 waves of
// 64 rows; h rings + x pre-packed in MFMA-fragment order [ks][mq][kg][64r][8]
// so a wave's per-k-step slice is 4 KB contiguous. Ring/fence/tree-barrier
// semantics identical to verified rounds 5-8.

#define BATCH 128
#define SEQ   512
#define INP   512
#define HID   1024
#define NCOL  4096
#define NB    256
#define KS0   48
#define KS1   64
#define HS_   (BATCH * HID)

typedef __bf16 bf16x8 __attribute__((ext_vector_type(8)));
typedef float  f32x4  __attribute__((ext_vector_type(4)));
typedef unsigned int u32x4 __attribute__((ext_vector_type(4)));
typedef unsigned long long u64;
typedef u64 u64x2 __attribute__((ext_vector_type(2)));

__device__ __forceinline__ bf16x8 load_bf16x8(const __hip_bfloat16* p) {
    u32x4 u = *reinterpret_cast<const u32x4*>(p);
    return __builtin_bit_cast(bf16x8, u);
}
__device__ __forceinline__ bf16x8 aload_bf16x8(const __hip_bfloat16* p) {
    u64x2 q;
    q[0] = __hip_atomic_load((const u64*)p,       __ATOMIC_RELAXED, __HIP_MEMORY_SCOPE_AGENT);
    q[1] = __hip_atomic_load((const u64*)(p + 4), __ATOMIC_RELAXED, __HIP_MEMORY_SCOPE_AGENT);
    return __builtin_bit_cast(bf16x8, q);
}
__device__ __forceinline__ f32x4 mfma16(bf16x8 a, bf16x8 b, f32x4 c) {
    return __builtin_amdgcn_mfma_f32_16x16x32_bf16(a, b, c, 0, 0, 0);
}
__device__ __forceinline__ float sigmoidf_(float x) {
    return 1.0f / (1.0f + __expf(-x));
}
__device__ __forceinline__ float tanhf_(float x) {
    return 1.0f - 2.0f / (__expf(2.0f * x) + 1.0f);
}
// global -> LDS async copy, 16 B per lane; LDS dest = l + lane*16 (HW rule)
__device__ __forceinline__ void gload16(const void* g, void* l) {
    __builtin_amdgcn_global_load_lds(
        (const __attribute__((address_space(1))) uint32_t*)g,
        (__attribute__((address_space(3))) uint32_t*)l, 16, 0, 0);
}
#define VMWAIT asm volatile("s_waitcnt vmcnt(12)" ::: "memory")

// ---------------------------------------------------------------------------
// Prep kernels. pack_frag/bias_reorder verified rounds 2-8 (unchanged).
// ---------------------------------------------------------------------------
template<int Ks>
__global__ __launch_bounds__(1024)
void pack_frag_kernel(const float* __restrict__ W, __hip_bfloat16* __restrict__ F)
{
    __shared__ float tile[32][33];
    const int k0 = blockIdx.x * 32;
    const int c0 = blockIdx.y * 32;
    const int tx = threadIdx.x & 31, ty = threadIdx.x >> 5;
    tile[ty][tx] = W[(size_t)(k0 + ty) * NCOL + (c0 + tx)];
    __syncthreads();
    const int cL  = threadIdx.x >> 5;
    const int kgw = (threadIdx.x >> 3) & 3;
    const int j   = threadIdx.x & 7;
    const int c   = c0 + cL;
    const int r   = (c & 1023) * 4 + (c >> 10);
    const int nb2 = r >> 4, cl = r & 15;
    const int ks  = k0 >> 5;
    const size_t chunk = ((size_t)(nb2 * Ks + ks) * 4 + kgw) * 16 + cl;
    F[chunk * 8 + j] = __float2bfloat16(tile[kgw * 8 + j][cL]);
}

__global__ void bias_reorder_kernel(const float* __restrict__ b0,
                                    const float* __restrict__ b1,
                                    float* __restrict__ b0r,
                                    float* __restrict__ b1r)
{
    int i = blockIdx.x * blockDim.x + threadIdx.x;
    if (i >= 2 * NCOL) return;
    const float* src = (i < NCOL) ? b0 : b1;
    float*       dst = (i < NCOL) ? b0r : b1r;
    int c = i & (NCOL - 1);
    dst[(c & 1023) * 4 + (c >> 10)] = src[c];
}

// x -> bf16 in fragment order: xb[t*65536 + (((ks*2+mq)*4+kg)*64+r)*8 + j]
//   = x[b = mq*64+r][t][k = ks*32+kg*8+j]
__global__ __launch_bounds__(256)
void xconv_kernel(const float* __restrict__ x, __hip_bfloat16* __restrict__ xb)
{
    const int idx = blockIdx.x * 256 + threadIdx.x;     // 4,194,304 total
    const int r   = idx & 63;
    const int kg  = (idx >> 6) & 3;
    const int mq  = (idx >> 8) & 1;
    const int ks  = (idx >> 9) & 15;
    const int t   = idx >> 13;
    const float* src = x + ((size_t)(mq * 64 + r) * SEQ + t) * INP + ks * 32 + kg * 8;
    bf16x8 v;
    #pragma unroll
    for (int j = 0; j < 8; ++j) v[j] = (__bf16)src[j];
    *reinterpret_cast<u32x4*>(xb + (size_t)idx * 8) = __builtin_bit_cast(u32x4, v);
}

// ---------------------------------------------------------------------------
// Persistent kernel: 256 blocks x 512 threads (8 waves: kq 0..3 x mq 0..1).
// ---------------------------------------------------------------------------
__global__ __launch_bounds__(512, 2)
void lstm_persistent(const __hip_bfloat16* __restrict__ xb,
                     const __hip_bfloat16* __restrict__ F0,
                     const __hip_bfloat16* __restrict__ F1,
                     const float* __restrict__ b0r,
                     const float* __restrict__ b1r,
                     const float* __restrict__ Wout,
                     const float* __restrict__ bout,
                     __hip_bfloat16* __restrict__ h0r,
                     __hip_bfloat16* __restrict__ h1r,
                     float* __restrict__ out,
                     int* __restrict__ bar,
                     int rm, int fm)
{
    extern __shared__ char smem[];                 // 8 waves x 16 KB staging

    __shared__ float zacc[2][128][17];             // 17408 B
    __shared__ float cS[2][512];                   // 4096 B
    __shared__ float biasS[2][16];                 // 128 B
    __shared__ __hip_bfloat16 hstage[2][128][4];   // 2048 B

    const int tid  = threadIdx.x;
    const int lane = tid & 63;
    const int wv   = tid >> 6;          // 0..7
    const int kq   = wv & 3;
    const int mq   = wv >> 2;           // 0..1
    const int lm   = lane & 15;
    const int kg   = lane >> 4;
    const int nb   = blockIdx.x;
    const uint32_t sbase = (uint32_t)wv * 16384;

    // ---- one-time init: B-fragments into registers (phase-invariant) ----
    bf16x8 B0r_[12], B1r_[16];
    #pragma unroll
    for (int i = 0; i < 4; ++i)
        B0r_[i]     = load_bf16x8(F0 + ((((size_t)nb * KS0 + (4*kq + i)) * 4 + kg) * 16 + lm) * 8);
    #pragma unroll
    for (int i = 0; i < 8; ++i)
        B0r_[4 + i] = load_bf16x8(F0 + ((((size_t)nb * KS0 + (16 + 8*kq + i)) * 4 + kg) * 16 + lm) * 8);
    #pragma unroll
    for (int i = 0; i < 8; ++i)
        B1r_[i]     = load_bf16x8(F1 + ((((size_t)nb * KS1 + (8*kq + i)) * 4 + kg) * 16 + lm) * 8);
    #pragma unroll
    for (int i = 0; i < 8; ++i)
        B1r_[8 + i] = load_bf16x8(F1 + ((((size_t)nb * KS1 + (32 + 8*kq + i)) * 4 + kg) * 16 + lm) * 8);

    if (tid < 32) biasS[tid >> 4][tid & 15] = ((tid < 16) ? b0r : b1r)[nb * 16 + (tid & 15)];
    for (int i = tid; i < 1024; i += 512) cS[i >> 9][i & 511] = 0.f;
    for (int i = tid; i < 2 * 128 * 17; i += 512) ((float*)zacc)[i] = 0.f;
    __syncthreads();

    auto issueStep = [&](const __hip_bfloat16* src, int sl) {
        const char* g = (const char*)src + (size_t)lane * 16;
        char* l = smem + sbase + (uint32_t)sl * 4096;
        #pragma unroll
        for (int i2 = 0; i2 < 4; ++i2)
            gload16(g + i2 * 1024, l + i2 * 1024);
    };
    auto readA = [&](int sl, int f) -> bf16x8 {
        const char* lp = smem + sbase + (uint32_t)sl * 4096
                       + (uint32_t)kg * 1024 + (uint32_t)f * 256 + (uint32_t)lm * 16;
        u32x4 v = *(const u32x4*)lp;
        return __builtin_bit_cast(bf16x8, v);
    };

    // prologue: x(t=0) steps 0..3 -> slots 0..3
    #pragma unroll
    for (int s = 0; s < 4; ++s)
        issueStep(xb + ((size_t)((4*kq + s) * 2 + mq)) * 2048, s);

    for (int p = 0; p <= SEQ; ++p) {
        const __hip_bfloat16* h0p = h0r + (size_t)((p + rm)     & rm) * HS_;  // h0(p-1)
        const __hip_bfloat16* h1p = h1r + (size_t)((p + rm - 1) & rm) * HS_;  // h1(p-2)
        __hip_bfloat16*       h0w = h0r + (size_t)( p           & rm) * HS_;  // h0(p)
        __hip_bfloat16*       h1w = h1r + (size_t)((p + rm)     & rm) * HS_;  // h1(p-1)
        const int tn = (p + 1 < SEQ) ? (p + 1) : (SEQ - 1);

        f32x4 aL0[4], aL1[4];
        #pragma unroll
        for (int f = 0; f < 4; ++f) { aL0[f] = f32x4{0,0,0,0}; aL1[f] = f32x4{0,0,0,0}; }

        // ---- x section: consume steps 0..3, issue h0 steps 0..3 ----
        #pragma unroll
        for (int s = 0; s < 4; ++s) {
            VMWAIT;
            bf16x8 A[4];
            #pragma unroll
            for (int f = 0; f < 4; ++f) A[f] = readA(s, f);
            #pragma unroll
            for (int f = 0; f < 4; ++f) aL0[f] = mfma16(A[f], B0r_[s], aL0[f]);
            issueStep(h0p + ((size_t)((8*kq + s) * 2 + mq)) * 2048, s);  // step 4+s
        }
        // ---- h0 section: consume steps 4..11 (dual MFMA), issue h0 4..7 / h1 0..3 ----
        #pragma unroll
        for (int i = 0; i < 8; ++i) {
            VMWAIT;
            const int sl = (4 + i) & 3;
            bf16x8 A[4];
            #pragma unroll
            for (int f = 0; f < 4; ++f) A[f] = readA(sl, f);
            #pragma unroll
            for (int f = 0; f < 4; ++f) {
                aL0[f] = mfma16(A[f], B0r_[4 + i], aL0[f]);
                aL1[f] = mfma16(A[f], B1r_[i],     aL1[f]);
            }
            if (i < 4) issueStep(h0p + ((size_t)((8*kq + 4 + i)   * 2 + mq)) * 2048, (8 + i) & 3);
            else       issueStep(h1p + ((size_t)((8*kq + (i - 4)) * 2 + mq)) * 2048, (8 + i) & 3);
        }
        // ---- h1 section: consume steps 12..19, issue h1 4..7 / next-phase x ----
        #pragma unroll
        for (int i = 0; i < 8; ++i) {
            VMWAIT;
            const int sl = (12 + i) & 3;
            bf16x8 A[4];
            #pragma unroll
            for (int f = 0; f < 4; ++f) A[f] = readA(sl, f);
            #pragma unroll
            for (int f = 0; f < 4; ++f) aL1[f] = mfma16(A[f], B1r_[8 + i], aL1[f]);
            if (i < 4)
                issueStep(h1p + ((size_t)((8*kq + 4 + i) * 2 + mq)) * 2048, (16 + i) & 3);
            else if (p < SEQ)
                issueStep(xb + (size_t)tn * 65536
                             + ((size_t)((4*kq + (i - 4)) * 2 + mq)) * 2048, (16 + i) & 3);
        }

        // ---- z partial reduction (LDS atomics; 4 kq waves per cell) ----
        if (p < SEQ) {
            #pragma unroll
            for (int f = 0; f < 4; ++f)
                #pragma unroll
                for (int r = 0; r < 4; ++r)
                    atomicAdd(&zacc[0][mq*64 + f*16 + kg*4 + r][lm], aL0[f][r]);
        }
        if (p >= 1) {
            #pragma unroll
            for (int f = 0; f < 4; ++f)
                #pragma unroll
                for (int r = 0; r < 4; ++r)
                    atomicAdd(&zacc[1][mq*64 + f*16 + kg*4 + r][lm], aL1[f][r]);
        }
        __syncthreads();

        // ---- gates (1024 units over 512 threads) ----
        for (int it = tid; it < 1024; it += 512) {
            const int L   = it >> 9;
            const int idx = it & 511;
            const int bl  = idx >> 2;
            const int u   = idx & 3;
            const bool act = L ? (p >= 1) : (p < SEQ);
            if (act) {
                float* zb = &zacc[L][bl][4 * u];
                const float zf = zb[0] + biasS[L][4*u + 0];
                const float zi = zb[1] + biasS[L][4*u + 1];
                const float zo = zb[2] + biasS[L][4*u + 2];
                const float zg = zb[3] + biasS[L][4*u + 3];
                zb[0] = 0.f; zb[1] = 0.f; zb[2] = 0.f; zb[3] = 0.f;
                const float cold = cS[L][idx];
                const float cn = sigmoidf_(zf) * cold + sigmoidf_(zi) * tanhf_(zg);
                const float hn = sigmoidf_(zo) * tanhf_(cn);
                cS[L][idx] = cn;
                hstage[L][bl][u] = __float2bfloat16(hn);
            }
        }
        __syncthreads();

        // ---- 8B bypass stores of h into fragment-ordered ring ----
        if (tid < 256) {
            const int L  = tid >> 7;
            const int bl = tid & 127;
            const bool act = L ? (p >= 1) : (p < SEQ);
            if (act) {
                __hip_bfloat16* hw = L ? h1w : h0w;
                const int uks = nb >> 3, ukg = (nb >> 1) & 3, jb = (nb & 1) * 4;
                const int mqb = bl >> 6, rr = bl & 63;
                const size_t e = ((size_t)((uks*2 + mqb)*4 + ukg)*64 + rr)*8 + jb;
                const u64 v = *(const u64*)&hstage[L][bl][0];
                __hip_atomic_store((u64*)(hw + e), v,
                                   __ATOMIC_RELAXED, __HIP_MEMORY_SCOPE_AGENT);
            }
        }
        __syncthreads();   // drains vmcnt for every wave -> stores at L3

        // ---- low-contention tree barrier (verified r7/r8) ----
        if (tid == 0) {
            const int g = nb >> 5;
            int* arrv = bar + 32 * g;
            int* root = bar + 256;
            int* rel  = bar + 512 + 32 * g;
            const int e = p + 1;
            __hip_atomic_fetch_add(arrv, 1, __ATOMIC_RELAXED, __HIP_MEMORY_SCOPE_AGENT);
            if ((nb & 31) == 0) {
                while (__hip_atomic_load(arrv, __ATOMIC_RELAXED, __HIP_MEMORY_SCOPE_AGENT) < 32 * e)
                    __builtin_amdgcn_s_sleep(1);
                __hip_atomic_fetch_add(root, 1, __ATOMIC_RELAXED, __HIP_MEMORY_SCOPE_AGENT);
            }
            if (nb == 0) {
                while (__hip_atomic_load(root, __ATOMIC_RELAXED, __HIP_MEMORY_SCOPE_AGENT) < 8 * e)
                    __builtin_amdgcn_s_sleep(1);
                #pragma unroll
                for (int gg = 0; gg < 8; ++gg)
                    __hip_atomic_store(bar + 512 + 32 * gg, e,
                                       __ATOMIC_RELAXED, __HIP_MEMORY_SCOPE_AGENT);
            } else {
                while (__hip_atomic_load(rel, __ATOMIC_RELAXED, __HIP_MEMORY_SCOPE_AGENT) < e)
                    __builtin_amdgcn_s_sleep(2);
            }
            if ((p & fm) == fm)
                __builtin_amdgcn_fence(__ATOMIC_ACQUIRE, "agent");  // bound cache lifetime
            asm volatile("" ::: "memory");
        }
        __builtin_amdgcn_s_barrier();   // raw: no extra vmcnt drain
    }

    // ---- head: out[b] = sigmoid(h1(511) . Wout + bout) ----
    if (nb == 0 && tid < BATCH) {
        const __hip_bfloat16* hb = h1r + (size_t)((SEQ - 1) & rm) * HS_;
        const int mqb = tid >> 6, rr = tid & 63;
        float acc = 0.f;
        for (int uu = 0; uu < HID; uu += 8) {
            const int uks = uu >> 5, ukg = (uu >> 3) & 3;
            const size_t e = ((size_t)((uks*2 + mqb)*4 + ukg)*64 + rr)*8;
            bf16x8 v = aload_bf16x8(hb + e);
            #pragma unroll
            for (int j = 0; j < 8; ++j) acc += (float)v[j] * Wout[uu + j];
        }
        out[tid] = 1.f / (1.f + __expf(-(acc + bout[0])));
    }
}

// ---------------------------------------------------------------------------
extern "C" void kernel_launch(void* const* d_in, const int* in_sizes, int n_in,
                              void* d_out, int out_size, void* d_ws, size_t ws_size,
                              hipStream_t stream)
{
    const float* x    = (const float*)d_in[0];
    const float* W0   = (const float*)d_in[1];
    const float* b0   = (const float*)d_in[2];
    const float* W1   = (const float*)d_in[3];
    const float* b1   = (const float*)d_in[4];
    const float* Wout = (const float*)d_in[5];
    const float* bout = (const float*)d_in[6];
    float* out = (float*)d_out;

    char* ws = (char*)d_ws;
    const size_t OFF_F0  = 0;            // 12,582,912
    const size_t OFF_F1  = 12582912;     // +16,777,216 -> 29,360,128
    const size_t OFF_B0R = 29360128;
    const size_t OFF_B1R = 29376512;
    const size_t OFF_BAR = 29392896;     // 4096
    const size_t OFF_R0  = 29396992;
    const size_t SLOT    = 262144;       // 128*1024*2 B
    const size_t XBYTES  = (size_t)BATCH * SEQ * INP * 2;   // 67,108,864

    // ring-size tiers by available workspace (all correct; bigger = faster)
    int rm, fm;
    if      (ws_size >= OFF_R0 + 128 * SLOT + XBYTES) { rm = 63; fm = 31; }
    else if (ws_size >= OFF_R0 +  32 * SLOT + XBYTES) { rm = 15; fm = 7;  }
    else                                              { rm = 1;  fm = 0;  }
    const size_t OFF_R1 = OFF_R0 + (size_t)(rm + 1) * SLOT;
    const size_t OFF_XB = OFF_R1 + (size_t)(rm + 1) * SLOT;

    __hip_bfloat16* F0  = (__hip_bfloat16*)(ws + OFF_F0);
    __hip_bfloat16* F1  = (__hip_bfloat16*)(ws + OFF_F1);
    float* b0r = (float*)(ws + OFF_B0R);
    float* b1r = (float*)(ws + OFF_B1R);
    __hip_bfloat16* h0r = (__hip_bfloat16*)(ws + OFF_R0);
    __hip_bfloat16* h1r = (__hip_bfloat16*)(ws + OFF_R1);
    int* bar = (int*)(ws + OFF_BAR);
    __hip_bfloat16* xbp = (__hip_bfloat16*)(ws + OFF_XB);

    // per-call reset: barrier epochs + the t=-1 ring slots (slot rm)
    hipMemsetAsync(ws + OFF_BAR, 0, 4096, stream);
    hipMemsetAsync(ws + OFF_R0 + (size_t)rm * SLOT, 0, SLOT, stream);
    hipMemsetAsync(ws + OFF_R1 + (size_t)rm * SLOT, 0, SLOT, stream);

    pack_frag_kernel<KS0><<<dim3(48, 128), 1024, 0, stream>>>(W0, F0);
    pack_frag_kernel<KS1><<<dim3(64, 128), 1024, 0, stream>>>(W1, F1);
    bias_reorder_kernel<<<32, 256, 0, stream>>>(b0, b1, b0r, b1r);
    xconv_kernel<<<(BATCH * SEQ * INP) / (256 * 8), 256, 0, stream>>>(x, xbp);

    hipFuncSetAttribute((const void*)lstm_persistent,
                        hipFuncAttributeMaxDynamicSharedMemorySize, 131072);

    void* args[] = {(void*)&xbp, (void*)&F0, (void*)&F1, (void*)&b0r, (void*)&b1r,
                    (void*)&Wout, (void*)&bout, (void*)&h0r, (void*)&h1r,
                    (void*)&out, (void*)&bar, (void*)&rm, (void*)&fm};
    hipLaunchCooperativeKernel((void*)lstm_persistent, dim3(NB), dim3(512),
                               args, 131072, stream);
}